// Round 1
// baseline (1041.837 us; speedup 1.0000x reference)
//
#include <hip/hip_runtime.h>

#define TEMP 10.0f

// ws layout (floats): Z[N] | sumQ[N*4] | sumL[N]
__global__ void spt_edge_kernel(const float* __restrict__ node_levels,
                                const float4* __restrict__ node_q,
                                const float4* __restrict__ edge_rel_q,
                                const float* __restrict__ edge_w,
                                const int* __restrict__ src,
                                const int* __restrict__ dst,
                                float* __restrict__ wsZ,
                                float* __restrict__ wsQ,   // [N*4]
                                float* __restrict__ wsL,
                                int E) {
    int e = blockIdx.x * blockDim.x + threadIdx.x;
    if (e >= E) return;

    int s = src[e];
    int d = dst[e];
    float l = node_levels[s];
    float w = edge_w[e];
    float p = __expf(TEMP * w * l);     // unnormalized softmax weight; cost in [0,10)

    float4 a = edge_rel_q[e];           // (w,x,y,z) in (.x,.y,.z,.w)
    float4 b = node_q[s];

    // Hamilton product a*b
    float ow = a.x*b.x - a.y*b.y - a.z*b.z - a.w*b.w;
    float ox = a.x*b.y + a.y*b.x + a.z*b.w - a.w*b.z;
    float oy = a.x*b.z - a.y*b.w + a.z*b.x + a.w*b.y;
    float oz = a.x*b.w + a.y*b.z - a.z*b.y + a.w*b.x;

    float* q = wsQ + 4 * (long long)d;
    atomicAdd(&wsZ[d], p);
    atomicAdd(q + 0, p * ow);
    atomicAdd(q + 1, p * ox);
    atomicAdd(q + 2, p * oy);
    atomicAdd(q + 3, p * oz);
    atomicAdd(&wsL[d], p * l);
}

__global__ void spt_node_kernel(const float* __restrict__ node_levels,
                                const float4* __restrict__ node_q,
                                const float* __restrict__ wsZ,
                                const float4* __restrict__ wsQ,
                                const float* __restrict__ wsL,
                                float4* __restrict__ out_q,
                                float* __restrict__ out_l,
                                int N) {
    int n = blockIdx.x * blockDim.x + threadIdx.x;
    if (n >= N) return;

    float l = node_levels[n];
    float ps = __expf(TEMP * l);        // self term (w = 1)
    float Z = wsZ[n] + ps;

    float4 sq = wsQ[n];
    float4 q = node_q[n];
    sq.x += ps * q.x;
    sq.y += ps * q.y;
    sq.z += ps * q.z;
    sq.w += ps * q.w;
    float sl = wsL[n] + ps * l;

    float inv = 1.0f / Z;
    float qw = sq.x * inv, qx = sq.y * inv, qy = sq.z * inv, qz = sq.w * inv;
    float norm = sqrtf(qw*qw + qx*qx + qy*qy + qz*qz);
    norm = fmaxf(norm, 1e-12f);
    float rn = 1.0f / norm;

    out_q[n] = make_float4(qw * rn, qx * rn, qy * rn, qz * rn);
    out_l[n] = sl * inv;
}

extern "C" void kernel_launch(void* const* d_in, const int* in_sizes, int n_in,
                              void* d_out, int out_size, void* d_ws, size_t ws_size,
                              hipStream_t stream) {
    const float*  node_levels = (const float*)d_in[0];
    const float4* node_q      = (const float4*)d_in[1];
    const float4* edge_rel_q  = (const float4*)d_in[2];
    const float*  edge_w      = (const float*)d_in[3];
    const int*    src         = (const int*)d_in[4];
    const int*    dst         = (const int*)d_in[5];

    const int N = in_sizes[0];        // node_levels count
    const int E = in_sizes[3];        // edge_w count

    float* wsZ = (float*)d_ws;        // N floats
    float* wsQ = wsZ + N;             // 4N floats (byte offset 4N -> 16B aligned for N%4==0)
    float* wsL = wsQ + 4 * (long long)N; // N floats

    hipMemsetAsync(d_ws, 0, (size_t)6 * N * sizeof(float), stream);

    int tpb = 256;
    spt_edge_kernel<<<(E + tpb - 1) / tpb, tpb, 0, stream>>>(
        node_levels, node_q, edge_rel_q, edge_w, src, dst, wsZ, wsQ, wsL, E);

    spt_node_kernel<<<(N + tpb - 1) / tpb, tpb, 0, stream>>>(
        node_levels, node_q, wsZ, (const float4*)wsQ, wsL,
        (float4*)d_out, (float*)d_out + 4 * (long long)N, N);
}